// Round 4
// baseline (8584.505 us; speedup 1.0000x reference)
//
#include <hip/hip_runtime.h>
#include <math.h>

#define B_ 64
#define T_ 100
#define S_ 32
#define L_ 128
#define R_ 16
#define H_ 256

__device__ __forceinline__ float dot4(float4 a, float4 b) {
  return a.x*b.x + a.y*b.y + a.z*b.z + a.w*b.w;
}
__device__ __forceinline__ void wave_fence() {
  asm volatile("s_waitcnt lgkmcnt(0)" ::: "memory");
  __builtin_amdgcn_wave_barrier();
}

// ---- 16x16 cholesky (row-per-lane, shfl) + explicit G = inv(L) ---- (verified r1)
__device__ __forceinline__ void chol16_inv(int lane, float (*C2)[17], float (*G)[17], float* rd) {
  float row[16];
  #pragma unroll
  for (int c = 0; c < 16; ++c) row[c] = (lane < 16) ? C2[lane][c] : 0.0f;
  float rdg = 0.0f;
  #pragma unroll
  for (int j = 0; j < 16; ++j) {
    float dsq = __shfl(row[j], j);
    float d = sqrtf(dsq);
    float inv = 1.0f / d;
    float cij = row[j] * inv;
    if (lane == j) { cij = d; rdg = inv; }
    row[j] = cij;
    float upd = (lane > j) ? (cij * inv) : 0.0f;
    #pragma unroll
    for (int c = j + 1; c < 16; ++c) {
      float cjc = __shfl(row[c], j);
      row[c] -= upd * cjc;
    }
  }
  if (lane < 16) {
    #pragma unroll
    for (int c = 0; c < 16; ++c) C2[lane][c] = row[c];
    rd[lane] = rdg;
  }
  wave_fence();
  if (lane < 16) {
    const int c = lane;
    float g[16];
    #pragma unroll
    for (int i = 0; i < 16; ++i) {
      float a = (i == c) ? 1.0f : 0.0f;
      #pragma unroll
      for (int j2 = 0; j2 < 16; ++j2) if (j2 < i) a -= C2[i][j2] * g[j2];
      g[i] = a * rd[i];
    }
    #pragma unroll
    for (int i = 0; i < 16; ++i) G[i][c] = (i >= c) ? g[i] : 0.0f;
  }
  wave_fence();
}

// ---- 32x32 cholesky + full solve (L L^T) x = t1 -> xb, all-register backward ----
__device__ __forceinline__ void chol32_fs(int lane, float (*C)[33],
                                          const float* t1, float* xb) {
  float row[32];
  #pragma unroll
  for (int c = 0; c < 32; ++c) row[c] = (lane < 32) ? C[lane][c] : 0.0f;
  float rdg = 0.0f;
  #pragma unroll
  for (int j = 0; j < 32; ++j) {
    float dsq = __shfl(row[j], j);
    float d = sqrtf(dsq);
    float inv = 1.0f / d;
    float cij = row[j] * inv;
    if (lane == j) { cij = d; rdg = inv; }
    row[j] = cij;
    float upd = (lane > j) ? (cij * inv) : 0.0f;
    #pragma unroll
    for (int c = j + 1; c < 32; ++c) {
      float cjc = __shfl(row[c], j);
      row[c] -= upd * cjc;
    }
  }
  // forward solve L y = t1 (registers)
  float acc = (lane < 32) ? t1[lane] : 0.0f;
  #pragma unroll
  for (int j = 0; j < 32; ++j) {
    float xj = __shfl(acc, j) * __shfl(rdg, j);
    if (lane == j) acc = xj;
    else if (lane > j) acc -= row[j] * xj;
  }
  // write back L so each lane can grab its column
  if (lane < 32) {
    #pragma unroll
    for (int c = 0; c < 32; ++c) C[lane][c] = row[c];
  }
  wave_fence();
  float colT[32];
  #pragma unroll
  for (int j = 0; j < 32; ++j) colT[j] = (lane < 32) ? C[j][lane] : 0.0f; // L[j][lane]
  // backward solve L^T x = y, pure shfl
  float acc2 = acc;
  float xi = 0.0f;
  #pragma unroll
  for (int j = 31; j >= 0; --j) {
    float xj = __shfl(acc2, j) * __shfl(rdg, j);
    if (lane == j) xi = xj;
    if (lane < j) acc2 -= colT[j] * xj;
  }
  if (lane < 32) xb[lane] = xi;
  wave_fence();
}

__global__ __launch_bounds__(1024) void filter_kernel(
    const float* __restrict__ kg,   // (B,T,L)
    const float* __restrict__ Kg,   // (B,T,L,R)
    const float* __restrict__ m0g,  // (L)
    const float* __restrict__ Ppg,  // (L)
    const float* __restrict__ Qg,   // (L)
    const float* __restrict__ wp0,  // (S,B,L)
    const float* __restrict__ wf0,  // (S,B,R)
    const float* __restrict__ wp1s, // (T-1,S,B,S)
    const float* __restrict__ wp2s, // (T-1,S,B,L)
    const float* __restrict__ wfs,  // (T-1,S,B,R)
    const float* __restrict__ W1,   // (L,H) row-major
    const float* __restrict__ W2,   // (H,L) row-major
    float* __restrict__ out)        // (T,S,B,L)
{
  const int b = blockIdx.x;
  const int tid = threadIdx.x;

  __shared__ float zc[S_][132];     // carried z
  __shared__ float Ab[S_][264];     // tanh acts (H), later McQ (L)
  __shared__ float Mc[S_][132];     // centered particles (rows)
  __shared__ float McT[L_][33];     // transposed centered particles
  __shared__ float zp[S_][132];     // z_p_c, then (zp - K x)
  __shared__ float KtT[R_][132];    // K_t^T [r][l]
  __shared__ float w1b[S_][36];
  __shared__ float wfb[S_][20];
  __shared__ float C32m[32][33];
  __shared__ float C2m[16][17];
  __shared__ float Gm[16][17];
  __shared__ float KMm[16][36];
  __shared__ float v1b[S_][20];
  __shared__ float yb[S_][20];      // step-0 only
  __shared__ float xvb[S_][20];     // step-0 only
  __shared__ float red[32][17];
  __shared__ float mp[L_], u1[L_], hv[L_], uu[L_], mv[L_], trp[L_], ktv[L_];
  __shared__ float Qv[L_], iQ[L_], sQ[L_], Ppv[L_], sPp[L_], m0v[L_];
  __shared__ float t1v[32], tPh[32], xbuf[32];
  __shared__ float ttv[16], ssv[16], rd16[16], y2v[16];

  // ---------------- init ----------------
  if (tid < L_) {
    float q = Qg[tid];  Qv[tid] = q;  iQ[tid] = 1.0f / q;  sQ[tid] = sqrtf(q);
    float p = Ppg[tid]; Ppv[tid] = p; sPp[tid] = sqrtf(p);
    m0v[tid] = m0g[tid];
  }
  __syncthreads();

  // ---------------- step 0 ----------------
  {
    if (tid < 512) { // stage K0^T
      const float* Ksrc = Kg + (size_t)b * T_ * L_ * R_;
      float4 v = *(const float4*)(Ksrc + tid * 4);
      int l = (tid * 4) >> 4, r = (tid * 4) & 15;
      KtT[r+0][l] = v.x; KtT[r+1][l] = v.y; KtT[r+2][l] = v.z; KtT[r+3][l] = v.w;
    }
    { // zp0 = sqrt(Pp)*w_p0
      int s = tid >> 5, l = (tid & 31) * 4;
      float4 w = *(const float4*)(wp0 + ((size_t)s * B_ + b) * L_ + l);
      float4 p = *(const float4*)&sPp[l];
      *(float4*)&zp[s][l] = make_float4(w.x*p.x, w.y*p.y, w.z*p.z, w.w*p.w);
    }
    if (tid < 512) { int s = tid >> 4, r = tid & 15;
      wfb[s][r] = wf0[((size_t)s * B_ + b) * R_ + r]; }
    __syncthreads();

    if (tid < 256) { // M16 = I + K0^T (Pp o K0)
      int r1 = tid >> 4, r2 = tid & 15;
      if (r1 <= r2) {
        float acc = (r1 == r2) ? 1.0f : 0.0f;
        for (int lc = 0; lc < 32; ++lc) {
          float4 a = *(const float4*)&KtT[r1][lc*4];
          float4 c = *(const float4*)&KtT[r2][lc*4];
          float4 p = *(const float4*)&Ppv[lc*4];
          acc += a.x*c.x*p.x + a.y*c.y*p.y + a.z*c.z*p.z + a.w*c.w*p.w;
        }
        C2m[r1][r2] = acc; C2m[r2][r1] = acc;
      }
      if (tid < 128) hv[tid] = m0v[tid] / Ppv[tid] + kg[(size_t)b * T_ * L_ + tid];
    } else if (tid < 512) {
      int q2 = tid - 256, s = q2 >> 3, r = (q2 & 7) * 2;
      float a0 = wfb[s][r], a1 = wfb[s][r+1];
      for (int lc = 0; lc < 32; ++lc) {
        float4 zz = *(const float4*)&zp[s][lc*4];
        float4 ka = *(const float4*)&KtT[r][lc*4];
        float4 kb = *(const float4*)&KtT[r+1][lc*4];
        a0 += dot4(zz, ka); a1 += dot4(zz, kb);
      }
      v1b[s][r] = a0; v1b[s][r+1] = a1;
    }
    __syncthreads();
    if (tid < 64) chol16_inv(tid, C2m, Gm, rd16);
    __syncthreads();
    if (tid < 512) { // tt partials ; y = G v1
      { int r = tid & 15, g = tid >> 4;
        float4 a = *(const float4*)&KtT[r][g*4];
        float4 p = *(const float4*)&Ppv[g*4];
        float4 h4 = *(const float4*)&hv[g*4];
        red[g][r] = a.x*p.x*h4.x + a.y*p.y*h4.y + a.z*p.z*h4.z + a.w*p.w*h4.w; }
      { int s = tid >> 4, r = tid & 15;
        float a = 0;
        #pragma unroll
        for (int j = 0; j < 16; ++j) a += Gm[r][j] * v1b[s][j];
        yb[s][r] = a; }
    }
    __syncthreads();
    if (tid < 512) { int s = tid >> 4, r = tid & 15; // x = G^T y
      float a = 0;
      #pragma unroll
      for (int j = 0; j < 16; ++j) a += Gm[j][r] * yb[s][j];
      xvb[s][r] = a; }
    if (tid < 64) { // ss = G^T G tt
      if (tid < 16) { float a = 0;
        #pragma unroll
        for (int g = 0; g < 32; ++g) a += red[g][tid];
        ttv[tid] = a; }
      wave_fence();
      if (tid < 16) { float a = 0;
        #pragma unroll
        for (int j = 0; j < 16; ++j) a += Gm[tid][j] * ttv[j];
        y2v[tid] = a; }
      wave_fence();
      if (tid < 16) { float a = 0;
        #pragma unroll
        for (int j = 0; j < 16; ++j) a += Gm[j][tid] * y2v[j];
        ssv[tid] = a; }
    }
    __syncthreads();
    if (tid < 128) {   // m = Pp*(h - K0 ss)
      float a = hv[tid];
      #pragma unroll
      for (int r = 0; r < 16; ++r) a -= KtT[r][tid] * ssv[r];
      mv[tid] = Ppv[tid] * a;
    }
    __syncthreads();
    if (tid < 512) { // z0 = m + zp - K0 x ; store + carry
      int s = tid >> 4, l0 = (tid & 15) * 8;
      float acc[8] = {0,0,0,0,0,0,0,0};
      #pragma unroll
      for (int r = 0; r < 16; ++r) {
        float xr = xvb[s][r];
        float4 k1 = *(const float4*)&KtT[r][l0];
        float4 k2 = *(const float4*)&KtT[r][l0+4];
        acc[0] += k1.x*xr; acc[1] += k1.y*xr; acc[2] += k1.z*xr; acc[3] += k1.w*xr;
        acc[4] += k2.x*xr; acc[5] += k2.y*xr; acc[6] += k2.z*xr; acc[7] += k2.w*xr;
      }
      float4 o1, o2;
      o1.x = mv[l0+0] + zp[s][l0+0] - acc[0]; o1.y = mv[l0+1] + zp[s][l0+1] - acc[1];
      o1.z = mv[l0+2] + zp[s][l0+2] - acc[2]; o1.w = mv[l0+3] + zp[s][l0+3] - acc[3];
      o2.x = mv[l0+4] + zp[s][l0+4] - acc[4]; o2.y = mv[l0+5] + zp[s][l0+5] - acc[5];
      o2.z = mv[l0+6] + zp[s][l0+6] - acc[6]; o2.w = mv[l0+7] + zp[s][l0+7] - acc[7];
      *(float4*)&zc[s][l0] = o1; *(float4*)&zc[s][l0+4] = o2;
      float* orow = out + ((size_t)s * B_ + b) * L_ + l0;
      *(float4*)orow = o1; *(float4*)(orow + 4) = o2;
    }
    __syncthreads();
  }

  // ---------------- main loop ----------------
  for (int t = 1; t < T_; ++t) {
    // ---- stage (no barrier needed before GEMM1) ----
    if (tid < 512) {
      const float* Ksrc = Kg + ((size_t)b * T_ + t) * L_ * R_;
      float4 v = *(const float4*)(Ksrc + tid * 4);
      int l = (tid * 4) >> 4, r = (tid * 4) & 15;
      KtT[r+0][l] = v.x; KtT[r+1][l] = v.y; KtT[r+2][l] = v.z; KtT[r+3][l] = v.w;
      int s = tid >> 4, rr = tid & 15;
      wfb[s][rr] = wfs[(((size_t)(t-1) * S_ + s) * B_ + b) * R_ + rr];
      if (tid < 128) ktv[tid] = kg[((size_t)b * T_ + t) * L_ + tid];
    } else {
      int e = (tid - 512) * 2, s = e >> 5, j = e & 31;
      float2 v = *(const float2*)(wp1s + (((size_t)(t-1) * S_ + s) * B_ + b) * S_ + j);
      w1b[s][j] = v.x; w1b[s][j+1] = v.y;
    }

    { // ---- GEMM1: A = tanh(z @ W1), W1 rows streamed (L1-resident) ----
      int s = tid >> 5, h0 = (tid & 31) * 8;
      float acc[8] = {0,0,0,0,0,0,0,0};
      for (int lc = 0; lc < 32; ++lc) {
        float4 z4 = *(const float4*)&zc[s][lc*4];
        const float* wbase = W1 + (size_t)(lc*4) * H_ + h0;
        float zv[4] = {z4.x, z4.y, z4.z, z4.w};
        #pragma unroll
        for (int q = 0; q < 4; ++q) {
          float4 wa = *(const float4*)(wbase + q*H_);
          float4 wb = *(const float4*)(wbase + q*H_ + 4);
          float zq = zv[q];
          acc[0] += zq*wa.x; acc[1] += zq*wa.y; acc[2] += zq*wa.z; acc[3] += zq*wa.w;
          acc[4] += zq*wb.x; acc[5] += zq*wb.y; acc[6] += zq*wb.z; acc[7] += zq*wb.w;
        }
      }
      #pragma unroll
      for (int j = 0; j < 8; ++j) Ab[s][h0 + j] = tanhf(acc[j]);
    }
    __syncthreads();
    { // ---- GEMM2: mth = z + A @ W2 ----
      int s = tid >> 5, l0 = (tid & 31) * 4;
      float acc[4] = {0,0,0,0};
      for (int hc = 0; hc < 64; ++hc) {
        float4 a4 = *(const float4*)&Ab[s][hc*4];
        const float* wbase = W2 + (size_t)(hc*4) * L_ + l0;
        float av[4] = {a4.x, a4.y, a4.z, a4.w};
        #pragma unroll
        for (int q = 0; q < 4; ++q) {
          float4 w = *(const float4*)(wbase + q*L_);
          float aq = av[q];
          acc[0] += aq*w.x; acc[1] += aq*w.y; acc[2] += aq*w.z; acc[3] += aq*w.w;
        }
      }
      float4 z4 = *(const float4*)&zc[s][l0];
      *(float4*)&Mc[s][l0] = make_float4(z4.x+acc[0], z4.y+acc[1], z4.z+acc[2], z4.w+acc[3]);
    }
    __syncthreads();
    if (tid < 128) { // ---- mean, u1 = mp/Q ----
      float m = 0;
      #pragma unroll 8
      for (int s = 0; s < 32; ++s) m += Mc[s][tid];
      m *= (1.0f / 32.0f);
      mp[tid] = m; u1[tid] = m * iQ[tid];
    }
    __syncthreads();
    { // ---- center: Mc, Ab=McQ, McT ----
      int s = tid >> 5, l0 = (tid & 31) * 4;
      float4 m4 = *(const float4*)&Mc[s][l0];
      float4 p4 = *(const float4*)&mp[l0];
      float4 q4 = *(const float4*)&iQ[l0];
      const float cs = 0.17677669529663687f;
      float4 v4 = make_float4((m4.x-p4.x)*cs, (m4.y-p4.y)*cs, (m4.z-p4.z)*cs, (m4.w-p4.w)*cs);
      *(float4*)&Mc[s][l0] = v4;
      *(float4*)&Ab[s][l0] = make_float4(v4.x*q4.x, v4.y*q4.y, v4.z*q4.z, v4.w*q4.w);
      McT[l0+0][s] = v4.x; McT[l0+1][s] = v4.y; McT[l0+2][s] = v4.z; McT[l0+3][s] = v4.w;
    }
    __syncthreads();
    { // ---- P5: C32 (sym) ; KM ; t1p ; zp ----
      { int s1 = tid >> 5, s2 = tid & 31;
        if (s1 <= s2) {
          float acc = (s1 == s2) ? 1.0f : 0.0f;
          for (int lc = 0; lc < 32; ++lc) {
            float4 a = *(const float4*)&Ab[s1][lc*4];
            float4 c = *(const float4*)&Mc[s2][lc*4];
            acc += dot4(a, c);
          }
          C32m[s1][s2] = acc; C32m[s2][s1] = acc;
        } }
      if (tid < 512) { int r = tid >> 5, s = tid & 31;   // KM[r][s]
        float acc = 0;
        for (int lc = 0; lc < 32; ++lc) {
          float4 kk = *(const float4*)&KtT[r][lc*4];
          float4 mm = *(const float4*)&Mc[s][lc*4];
          acc += dot4(kk, mm);
        }
        KMm[r][s] = acc;
      } else { int g = tid - 512, s = g >> 4, seg = g & 15; // t1 partials
        float4 m1 = *(const float4*)&Mc[s][seg*8];
        float4 m2 = *(const float4*)&Mc[s][seg*8+4];
        float4 a1 = *(const float4*)&u1[seg*8];
        float4 a2 = *(const float4*)&u1[seg*8+4];
        red[s][seg] = dot4(m1, a1) + dot4(m2, a2);
      }
      { // zp
        int s = tid >> 5, l0 = (tid & 31) * 4;
        float a0=0, a1=0, a2=0, a3=0;
        for (int j = 0; j < 32; ++j) {
          float wj = w1b[s][j];
          float4 m4 = *(const float4*)&Mc[j][l0];
          a0 += m4.x*wj; a1 += m4.y*wj; a2 += m4.z*wj; a3 += m4.w*wj;
        }
        const float* w2src = wp2s + (((size_t)(t-1) * S_ + s) * B_ + b) * L_ + l0;
        float4 wv = *(const float4*)(w2src);
        float4 q4 = *(const float4*)&sQ[l0];
        *(float4*)&zp[s][l0] = make_float4(a0+q4.x*wv.x, a1+q4.y*wv.y, a2+q4.z*wv.z, a3+q4.w*wv.w);
      }
    }
    __syncthreads();
    // ---- P6: KPK ; t1 reduce ; v1 ----
    if (tid < 256) {
      int r1 = tid >> 4, r2 = tid & 15;
      if (r1 <= r2) {
        float acc = (r1 == r2) ? 1.0f : 0.0f;
        #pragma unroll
        for (int sc2 = 0; sc2 < 8; ++sc2) {
          float4 a = *(const float4*)&KMm[r1][sc2*4];
          float4 c = *(const float4*)&KMm[r2][sc2*4];
          acc += dot4(a, c);
        }
        for (int lc = 0; lc < 32; ++lc) {
          float4 a = *(const float4*)&KtT[r1][lc*4];
          float4 c = *(const float4*)&KtT[r2][lc*4];
          float4 q = *(const float4*)&Qv[lc*4];
          acc += a.x*c.x*q.x + a.y*c.y*q.y + a.z*c.z*q.z + a.w*c.w*q.w;
        }
        C2m[r1][r2] = acc; C2m[r2][r1] = acc;
      }
    } else if (tid < 288) {
      int s = tid - 256;
      float a = 0;
      #pragma unroll
      for (int g = 0; g < 16; ++g) a += red[s][g];
      t1v[s] = a;
    } else if (tid >= 512) {
      int g = tid - 512, s = g >> 4, r = g & 15;
      float a = wfb[s][r];
      for (int lc = 0; lc < 32; ++lc) {
        float4 zz = *(const float4*)&zp[s][lc*4];
        float4 kk = *(const float4*)&KtT[r][lc*4];
        a += dot4(zz, kk);
      }
      v1b[s][r] = a;
    }
    __syncthreads();
    // ---- P7: wave0 chol32 full solve ; wave1 chol16+inv ----
    if (tid < 64) chol32_fs(tid, C32m, t1v, xbuf);
    else if (tid < 128) chol16_inv(tid - 64, C2m, Gm, rd16);
    __syncthreads();
    // ---- P8: wave0 = full h->m chain (fence-only) ; waves1-8 = y,x,(zp-Kx) ----
    if (tid < 64) {
      const int ln = tid;
      const int l0 = ln, l1 = ln + 64;
      // hv = u1 + k - iQ * (McT xbuf)
      float a0 = 0.f, a1 = 0.f;
      for (int s = 0; s < 32; ++s) {
        float xs = xbuf[s];
        a0 += McT[l0][s] * xs; a1 += McT[l1][s] * xs;
      }
      hv[l0] = u1[l0] + ktv[l0] - iQ[l0] * a0;
      hv[l1] = u1[l1] + ktv[l1] - iQ[l1] * a1;
      wave_fence();
      { // tPh[s] = Mc[s] . hv
        int s = ln & 31, hb = (ln >> 5) * 64;
        float p = 0;
        #pragma unroll
        for (int l = 0; l < 64; l += 4) {
          float4 m4 = *(const float4*)&Mc[s][hb+l];
          float4 h4 = *(const float4*)&hv[hb+l];
          p += dot4(m4, h4);
        }
        p += __shfl_xor(p, 32);
        if (ln < 32) tPh[s] = p;
      }
      wave_fence();
      // uu = Q*hv + McT tPh
      a0 = 0.f; a1 = 0.f;
      for (int s = 0; s < 32; ++s) {
        float ts = tPh[s];
        a0 += McT[l0][s] * ts; a1 += McT[l1][s] * ts;
      }
      uu[l0] = Qv[l0]*hv[l0] + a0;
      uu[l1] = Qv[l1]*hv[l1] + a1;
      wave_fence();
      // tt[r] = KtT[r] . uu  (4 quarter-partials, xor-reduce)
      float ttr;
      { int r = ln & 15, qd = ln >> 4;
        float p = 0;
        #pragma unroll
        for (int l = 0; l < 32; l += 4) {
          float4 k4 = *(const float4*)&KtT[r][qd*32+l];
          float4 u4 = *(const float4*)&uu[qd*32+l];
          p += dot4(k4, u4);
        }
        p += __shfl_xor(p, 16);
        p += __shfl_xor(p, 32);
        ttr = p;
      }
      // ss = G^T (G tt)
      { int r = ln & 15;
        float y2 = 0;
        #pragma unroll
        for (int j = 0; j < 16; ++j) y2 += Gm[r][j] * __shfl(ttr, j);
        float ssr = 0;
        #pragma unroll
        for (int j = 0; j < 16; ++j) ssr += Gm[j][r] * __shfl(y2, j);
        if (ln < 16) ssv[r] = ssr;
      }
      wave_fence();
      // trp = K ss
      a0 = 0.f; a1 = 0.f;
      #pragma unroll
      for (int r = 0; r < 16; ++r) {
        float sr = ssv[r];
        a0 += KtT[r][l0] * sr; a1 += KtT[r][l1] * sr;
      }
      trp[l0] = a0; trp[l1] = a1;
      wave_fence();
      { // tP2[s] = Mc[s] . trp  (reuse tPh)
        int s = ln & 31, hb = (ln >> 5) * 64;
        float p = 0;
        #pragma unroll
        for (int l = 0; l < 64; l += 4) {
          float4 m4 = *(const float4*)&Mc[s][hb+l];
          float4 h4 = *(const float4*)&trp[hb+l];
          p += dot4(m4, h4);
        }
        p += __shfl_xor(p, 32);
        if (ln < 32) tPh[s] = p;
      }
      wave_fence();
      // mv = uu - Q*trp - McT tP2
      a0 = 0.f; a1 = 0.f;
      for (int s = 0; s < 32; ++s) {
        float ts = tPh[s];
        a0 += McT[l0][s] * ts; a1 += McT[l1][s] * ts;
      }
      mv[l0] = uu[l0] - Qv[l0]*trp[l0] - a0;
      mv[l1] = uu[l1] - Qv[l1]*trp[l1] - a1;
    } else if (tid < 576) {
      int g = tid - 64;
      int s = g >> 4, r = g & 15;
      int sb = (g & 63) & 48;
      float yv = 0;
      #pragma unroll
      for (int j = 0; j < 16; ++j) yv += Gm[r][j] * v1b[s][j];
      float xr_ = 0;
      #pragma unroll
      for (int j = 0; j < 16; ++j) xr_ += Gm[j][r] * __shfl(yv, sb + j);
      float xl[16];
      #pragma unroll
      for (int j = 0; j < 16; ++j) xl[j] = __shfl(xr_, sb + j);
      // zp[s][lb..lb+7] -= K x   (in place)
      int lb = r * 8;
      float acc[8] = {0,0,0,0,0,0,0,0};
      #pragma unroll
      for (int r2 = 0; r2 < 16; ++r2) {
        float xr = xl[r2];
        #pragma unroll
        for (int i = 0; i < 8; ++i) acc[i] += KtT[r2][lb+i] * xr;
      }
      float4 z1 = *(const float4*)&zp[s][lb];
      float4 z2 = *(const float4*)&zp[s][lb+4];
      z1.x -= acc[0]; z1.y -= acc[1]; z1.z -= acc[2]; z1.w -= acc[3];
      z2.x -= acc[4]; z2.y -= acc[5]; z2.z -= acc[6]; z2.w -= acc[7];
      *(float4*)&zp[s][lb] = z1; *(float4*)&zp[s][lb+4] = z2;
    }
    __syncthreads();
    { // ---- store: z = mv + (zp - Kx) ----
      int s = tid >> 5, l0 = (tid & 31) * 4;
      float4 z4 = *(const float4*)&zp[s][l0];
      float4 m4 = *(const float4*)&mv[l0];
      z4.x += m4.x; z4.y += m4.y; z4.z += m4.z; z4.w += m4.w;
      *(float4*)&zc[s][l0] = z4;
      *(float4*)(out + (((size_t)t * S_ + s) * B_ + b) * L_ + l0) = z4;
    }
    __syncthreads();
  }
}

extern "C" void kernel_launch(void* const* d_in, const int* in_sizes, int n_in,
                              void* d_out, int out_size, void* d_ws, size_t ws_size,
                              hipStream_t stream) {
  const float* kg  = (const float*)d_in[0];
  const float* Kg  = (const float*)d_in[1];
  const float* m0  = (const float*)d_in[2];
  const float* Pp  = (const float*)d_in[3];
  const float* Qd  = (const float*)d_in[4];
  const float* W1  = (const float*)d_in[5];
  const float* W2  = (const float*)d_in[6];
  const float* wp0 = (const float*)d_in[7];
  const float* wf0 = (const float*)d_in[8];
  const float* wp1 = (const float*)d_in[9];
  const float* wp2 = (const float*)d_in[10];
  const float* wfs = (const float*)d_in[11];
  float* outp = (float*)d_out;
  (void)d_ws; (void)ws_size;

  filter_kernel<<<B_, 1024, 0, stream>>>(kg, Kg, m0, Pp, Qd, wp0, wf0,
                                         wp1, wp2, wfs, W1, W2, outp);
}